// Round 12
// baseline (134.503 us; speedup 1.0000x reference)
//
#include <hip/hip_runtime.h>

// Pairwise cosine similarity: C[i][j] = <x_i/||x_i||, y_j/||y_j||>
// x,y: [8192][512] f32.  Out: [8192][8192] f32.
// Stage 1: row-normalize -> bf16 in d_ws (fused single launch).
// Stage 2 (R12): BARRIER-FREE wave-independent GEMM. Each wave owns a
//   private 16KB LDS region (64KB/block, 2 blocks/CU) and an independent
//   64x64 output tile: private double-buffered staging via
//   global_load_lds, per-wave counted vmcnt(8) ledger, ZERO s_barrier /
//   __syncthreads anywhere. R4-R11 all kept barrier-synced phases and
//   converged at ~110us regardless of structure; this isolates the
//   barrier/convoy cost. If this also lands ~110, the ~5.5TB/s
//   mixed-stream memory ceiling is confirmed by elimination.
//   XOR swizzle (4-way aliasing = b128 throughput floor), XCD banding,
//   nt strip epilogue (wave-private, no sync).

typedef __attribute__((ext_vector_type(8))) short bf16x8;
typedef __attribute__((ext_vector_type(4))) float f32x4;
typedef __attribute__((ext_vector_type(8))) unsigned short ushort8;

#define M_DIM 8192
#define N_DIM 8192
#define K_DIM 512

static __device__ __forceinline__ unsigned short f32_to_bf16(float f) {
  unsigned int u = __float_as_uint(f);
  u = (u + 0x7FFFu + ((u >> 16) & 1u)) >> 16;  // round-to-nearest-even
  return (unsigned short)u;
}

// One wave per row; handles x rows [0,8192) and y rows [8192,16384).
__global__ __launch_bounds__(256) void normalize_rows(
    const float* __restrict__ x, const float* __restrict__ y,
    unsigned short* __restrict__ out) {
  const int wid = threadIdx.x >> 6;
  const int lane = threadIdx.x & 63;
  const int row = (blockIdx.x << 2) + wid;
  const float* src = row < M_DIM ? x + (size_t)row * K_DIM
                                 : y + (size_t)(row - M_DIM) * K_DIM;
  const float4* r = (const float4*)src;
  float4 v0 = r[lane * 2];
  float4 v1 = r[lane * 2 + 1];
  float ss = v0.x * v0.x + v0.y * v0.y + v0.z * v0.z + v0.w * v0.w +
             v1.x * v1.x + v1.y * v1.y + v1.z * v1.z + v1.w * v1.w;
#pragma unroll
  for (int off = 32; off; off >>= 1) ss += __shfl_xor(ss, off, 64);
  const float s = 1.0f / fmaxf(sqrtf(ss), 1e-8f);
  const float f[8] = {v0.x, v0.y, v0.z, v0.w, v1.x, v1.y, v1.z, v1.w};
  union { ushort8 v; unsigned short u[8]; } o;
#pragma unroll
  for (int i = 0; i < 8; ++i) o.u[i] = f32_to_bf16(f[i] * s);
  *(ushort8*)(out + (size_t)row * K_DIM + lane * 8) = o.v;
}

static __device__ __forceinline__ void gl16(const unsigned short* g, char* l) {
  __builtin_amdgcn_global_load_lds(
      (const __attribute__((address_space(1))) unsigned int*)g,
      (__attribute__((address_space(3))) unsigned int*)l, 16, 0, 0);
}

#define SBAR() __builtin_amdgcn_sched_barrier(0)
#define LGKM0() do { asm volatile("s_waitcnt lgkmcnt(0)" ::: "memory"); \
                     __builtin_amdgcn_sched_barrier(0); } while (0)
#define VMCNT(n) do { asm volatile("s_waitcnt vmcnt(" #n ")" ::: "memory"); \
                      __builtin_amdgcn_sched_barrier(0); } while (0)

// Per-wave LDS (16KB at smem + wid*16384): buf[2] (8KB stride) x
// {A 4KB, B 4KB}. Row r (0..63) at r*64B; 16B slot s at (s^(r&3))*16.
__global__ __launch_bounds__(256, 2) void cosgemm(
    const unsigned short* __restrict__ A,   // xn bf16 [8192][512]
    const unsigned short* __restrict__ B,   // yn bf16 [8192][512]
    float* __restrict__ C) {                // [8192][8192]
  extern __shared__ char smem[];  // 65536 B

  const int tid = threadIdx.x;
  const int lane = tid & 63;
  const int wid = tid >> 6;       // 0..3
  const int wm = wid >> 1;        // 0..1 (A half)
  const int wn = wid & 1;         // 0..1 (B half)
  const int lr16 = lane & 15;
  const int hq = lane >> 4;       // 0..3 (k slot)
  const int sw = hq ^ (lr16 & 3); // swizzled ds_read 16B slot

  // XCD banding: xcd = bid&7 owns 8 row-bands; sweep bx per band.
  const int bid = blockIdx.x;                 // 0..4095
  const int idx = bid >> 3;                   // 0..511
  const int by = ((bid & 7) << 3) + (idx & 7);    // 0..63
  const int bx = idx >> 3;                    // 0..63
  const int row0 = (by << 7) + (wm << 6);     // this wave's 64 A rows
  const int col0 = (bx << 7) + (wn << 6);     // this wave's 64 B rows

  // staging source: gl16 call c covers rows c*16 + (lane>>2),
  // global 16B slot = (lane&3) ^ (row&3).
  const int srl = lane >> 2;                 // 0..15
  const int ssl = (lane & 3) ^ (srl & 3);
  const unsigned short* pA = A + (size_t)(row0 + srl) * K_DIM + ssl * 8;
  const unsigned short* pB = B + (size_t)(col0 + srl) * K_DIM + ssl * 8;
  char* const myLds = smem + (wid << 14);

  auto stage = [&](int par, int T) {  // 8 gl16: full A(64xBK32) + B tile
    char* l = myLds + (par << 13);
#pragma unroll
    for (int c = 0; c < 4; ++c) {
      gl16(pA + T * 32 + (size_t)(c << 4) * K_DIM, l + (c << 10));
      gl16(pB + T * 32 + (size_t)(c << 4) * K_DIM, l + 4096 + (c << 10));
    }
  };

  bf16x8 af[4], bf[4];
  f32x4 acc[4][4] = {};

  auto ldAB = [&](int par) {  // 8 x ds_read_b128 (own region only)
#pragma unroll
    for (int m = 0; m < 4; ++m)
      af[m] = *(const bf16x8*)(myLds + (par << 13) + (m * 16 + lr16) * 64 +
                               (sw << 4));
#pragma unroll
    for (int n = 0; n < 4; ++n)
      bf[n] = *(const bf16x8*)(myLds + (par << 13) + 4096 +
                               (n * 16 + lr16) * 64 + (sw << 4));
  };
  auto mmAll = [&]() {  // 16 MFMA
    __builtin_amdgcn_s_setprio(1);
#pragma unroll
    for (int m = 0; m < 4; ++m)
#pragma unroll
      for (int n = 0; n < 4; ++n)
        acc[m][n] = __builtin_amdgcn_mfma_f32_16x16x32_bf16(af[m], bf[n],
                                                            acc[m][n], 0, 0, 0);
    __builtin_amdgcn_s_setprio(0);
  };

  // ---- wave-private pipeline, no barriers anywhere ----
  stage(0, 0);       // T0 -> buf0 (8 gl16)
  stage(1, 1);       // T1 -> buf1 (8)
  VMCNT(8);          // T0 landed (T1's 8 may remain in flight)

#pragma unroll 1
  for (int t = 0; t < 16; ++t) {
    const int cb = t & 1;
    ldAB(cb);        // reads of tile t (landed by ledger below)
    LGKM0();         // fragments in regs -> buf[cb] reusable
    if (t < 14) stage(cb, t + 2);   // overwrite with T(t+2)
    mmAll();         // MFMA overlaps the in-flight staging
    // ledger: after stage, outstanding = T(t+1)'s 8 + T(t+2)'s 8.
    // vmcnt(8) retires T(t+1) -> next iter's ldAB safe. Never 0 mid-loop.
    if (t < 14) { VMCNT(8); }
    else if (t == 14) { VMCNT(0); }  // T15 fully landed for final iter
  }

  // ---- epilogue: wave-private [16][68] f32 strip in own region ----
  float* S = (float*)myLds;
#pragma unroll
  for (int fm = 0; fm < 4; ++fm) {
#pragma unroll
    for (int fn = 0; fn < 4; ++fn)
#pragma unroll
      for (int q = 0; q < 4; ++q)
        S[(hq * 4 + q) * 68 + fn * 16 + lr16] = acc[fm][fn][q];
    LGKM0();  // own-wave scatter visible to own-wave reads
#pragma unroll
    for (int r = 0; r < 4; ++r) {
      f32x4 v = *(const f32x4*)&S[(r * 4 + hq) * 68 + lr16 * 4];
      __builtin_nontemporal_store(
          v, (f32x4*)&C[(size_t)(row0 + fm * 16 + r * 4 + hq) * N_DIM +
                        col0 + lr16 * 4]);
    }
    LGKM0();  // reads consumed before next fm's scatter reuses the strip
  }
}

extern "C" void kernel_launch(void* const* d_in, const int* in_sizes, int n_in,
                              void* d_out, int out_size, void* d_ws, size_t ws_size,
                              hipStream_t stream) {
  const float* x = (const float*)d_in[0];
  const float* y = (const float*)d_in[1];
  float* out = (float*)d_out;
  unsigned short* xn = (unsigned short*)d_ws;                    // 8 MB
  unsigned short* yn = xn + (size_t)M_DIM * K_DIM;               // 8 MB

  (void)hipFuncSetAttribute((const void*)cosgemm,
                            hipFuncAttributeMaxDynamicSharedMemorySize, 65536);

  normalize_rows<<<(M_DIM + N_DIM) / 4, 256, 0, stream>>>(x, y, xn);
  cosgemm<<<(M_DIM / 128) * (N_DIM / 128), 256, 65536, stream>>>(xn, yn, out);
}

// Round 13
// 109.810 us; speedup vs baseline: 1.2249x; 1.2249x over previous
//
#include <hip/hip_runtime.h>

// Pairwise cosine similarity: C[i][j] = <x_i/||x_i||, y_j/||y_j||>
// x,y: [8192][512] f32.  Out: [8192][8192] f32.
// Stage 1: row-normalize -> bf16 in d_ws (fused single launch).
// Stage 2: 256x128-tile BK=32 8-phase bf16 MFMA GEMM (R9-identical
//   pipeline: 4 waves, 48KB dbuf LDS, counted VMCNT(2), XOR swizzle,
//   setprio, nt strip epilogue).
// R13 change (single variable vs R9): block->tile mapping is a
//   bx-CHUNKED SERPENTINE within each XCD. R12's recount showed the
//   266MB FETCH ~= per-XCD B-panel re-reads (4 band-sweeps x 8MB x 8
//   XCDs), not output RMW (which explains all the null store
//   experiments). Chunk bx by 8 and sweep the 4 by-bands inside each
//   chunk: L2 working set = 1MB B-chunk + 1MB A-band < 4MB, so B is
//   read once per XCD -> operand HBM reads ~266MB -> ~70MB.

typedef __attribute__((ext_vector_type(8))) short bf16x8;
typedef __attribute__((ext_vector_type(4))) float f32x4;
typedef __attribute__((ext_vector_type(8))) unsigned short ushort8;

#define M_DIM 8192
#define N_DIM 8192
#define K_DIM 512

static __device__ __forceinline__ unsigned short f32_to_bf16(float f) {
  unsigned int u = __float_as_uint(f);
  u = (u + 0x7FFFu + ((u >> 16) & 1u)) >> 16;  // round-to-nearest-even
  return (unsigned short)u;
}

// One wave per row; handles x rows [0,8192) and y rows [8192,16384).
__global__ __launch_bounds__(256) void normalize_rows(
    const float* __restrict__ x, const float* __restrict__ y,
    unsigned short* __restrict__ out) {
  const int wid = threadIdx.x >> 6;
  const int lane = threadIdx.x & 63;
  const int row = (blockIdx.x << 2) + wid;
  const float* src = row < M_DIM ? x + (size_t)row * K_DIM
                                 : y + (size_t)(row - M_DIM) * K_DIM;
  const float4* r = (const float4*)src;
  float4 v0 = r[lane * 2];
  float4 v1 = r[lane * 2 + 1];
  float ss = v0.x * v0.x + v0.y * v0.y + v0.z * v0.z + v0.w * v0.w +
             v1.x * v1.x + v1.y * v1.y + v1.z * v1.z + v1.w * v1.w;
#pragma unroll
  for (int off = 32; off; off >>= 1) ss += __shfl_xor(ss, off, 64);
  const float s = 1.0f / fmaxf(sqrtf(ss), 1e-8f);
  const float f[8] = {v0.x, v0.y, v0.z, v0.w, v1.x, v1.y, v1.z, v1.w};
  union { ushort8 v; unsigned short u[8]; } o;
#pragma unroll
  for (int i = 0; i < 8; ++i) o.u[i] = f32_to_bf16(f[i] * s);
  *(ushort8*)(out + (size_t)row * K_DIM + lane * 8) = o.v;
}

static __device__ __forceinline__ void gl16(const unsigned short* g, char* l) {
  __builtin_amdgcn_global_load_lds(
      (const __attribute__((address_space(1))) unsigned int*)g,
      (__attribute__((address_space(3))) unsigned int*)l, 16, 0, 0);
}

#define BAR() __builtin_amdgcn_s_barrier()
#define SBAR() __builtin_amdgcn_sched_barrier(0)
#define LGKM0() do { asm volatile("s_waitcnt lgkmcnt(0)" ::: "memory"); \
                     __builtin_amdgcn_sched_barrier(0); } while (0)
#define VMCNT(n) do { asm volatile("s_waitcnt vmcnt(" #n ")" ::: "memory"); \
                      __builtin_amdgcn_sched_barrier(0); } while (0)

// LDS per parity p: base p*24576; A [0,16K): row r (0..255) at r*64,
// slot s (16B) stored at (s ^ (r&3))*16; B [16K,24K): row (0..127) same.
__global__ __launch_bounds__(256, 2) void cosgemm(
    const unsigned short* __restrict__ A,   // xn bf16 [8192][512]
    const unsigned short* __restrict__ B,   // yn bf16 [8192][512]
    float* __restrict__ C) {                // [8192][8192]
  extern __shared__ char smem[];  // 49152 B

  const int tid = threadIdx.x;
  const int lane = tid & 63;
  const int wid = tid >> 6;       // 0..3
  const int wm = wid >> 1;        // 0..1  (M half: 128 rows)
  const int wn = wid & 1;         // 0..1  (N half: 64 cols)
  const int lr16 = lane & 15;
  const int hq = lane >> 4;       // 0..3  (k slot)
  const int sw = hq ^ (lr16 & 3); // swizzled ds_read slot (uniform/lane)

  // R13 mapping: xcd = bid&7 owns by in {4x..4x+3} x bx 0..63.
  // Serpentine: 8 chunks of 8 bx; inside a chunk sweep all 4 by.
  const int bid = blockIdx.x;                // 0..2047
  const int xcd = bid & 7;
  const int i = bid >> 3;                    // 0..255
  const int c = i >> 5;                      // chunk 0..7
  const int r = i & 31;                      // 0..31 within chunk
  const int by = (xcd << 2) + (r & 3);       // 0..31
  const int bx = (c << 3) + (r >> 2);        // 0..63
  const int row0 = by << 8;                  // A rows (256)
  const int col0 = bx << 7;                  // B rows / C cols (128)

  // staging source: call covers row = base + c*16 + (lane>>2),
  // global 16B slot = (lane&3) ^ (row&3) = (lane&3) ^ ((lane>>2)&3).
  const int srl = lane >> 2;
  const int ssl = (lane & 3) ^ (srl & 3);
  const unsigned short* pA =
      A + (size_t)(row0 + (wid << 6) + srl) * K_DIM + ssl * 8;
  const unsigned short* pB =
      B + (size_t)(col0 + (wid << 5) + srl) * K_DIM + ssl * 8;

  // stageA2: 2 gl16 (32 rows); stageB1: 1 gl16 (16 rows). T = K-tile idx.
  auto stageA2 = [&](int par, int cpair, int T) {
    char* l = smem + par * 24576 + (wid << 12) + (cpair << 11);
    const unsigned short* g = pA + T * 32 + (size_t)(cpair << 5) * K_DIM;
    gl16(g, l);
    gl16(g + (size_t)16 * K_DIM, l + 1024);
  };
  auto stageB1 = [&](int par, int cc, int T) {
    char* l = smem + par * 24576 + 16384 + (wid << 11) + (cc << 10);
    gl16(pB + T * 32 + (size_t)(cc << 4) * K_DIM, l);
  };

  bf16x8 af[4], bf[4];
  f32x4 acc[8][4] = {};

  auto ldA = [&](int par, int fmBase) {   // 4 x ds_read_b128
#pragma unroll
    for (int j = 0; j < 4; ++j) {
      const int row = (wm << 7) + (fmBase + j) * 16 + lr16;
      af[j] = *(const bf16x8*)(smem + par * 24576 + row * 64 + (sw << 4));
    }
  };
  auto ldB = [&](int par, int fnBase) {   // 2 x ds_read_b128
#pragma unroll
    for (int j = 0; j < 2; ++j) {
      const int row = (wn << 6) + (fnBase + j) * 16 + lr16;
      bf[fnBase + j] =
          *(const bf16x8*)(smem + par * 24576 + 16384 + row * 64 + (sw << 4));
    }
  };
  auto mm = [&](int fmBase, int fnBase) {  // 8 MFMA
    __builtin_amdgcn_s_setprio(1);
#pragma unroll
    for (int m = 0; m < 4; ++m)
#pragma unroll
      for (int n = 0; n < 2; ++n)
        acc[fmBase + m][fnBase + n] = __builtin_amdgcn_mfma_f32_16x16x32_bf16(
            af[m], bf[fnBase + n], acc[fmBase + m][fnBase + n], 0, 0, 0);
    __builtin_amdgcn_s_setprio(0);
  };

  // ---- prologue: A(0), B(0), B(1); VMCNT(2) -> tile0 landed
  stageA2(0, 0, 0); stageA2(0, 1, 0);
  stageB1(0, 0, 0); stageB1(0, 1, 0);
  stageB1(1, 0, 1); stageB1(1, 1, 1);
  VMCNT(2);
  BAR(); SBAR();

  // per-wave outstanding tracking (issue order, in-order retirement):
  // steady P4: B(u)2,A(u)4,B(t+2)2=8 -> VMCNT(2) leaves B(t+2).
  // steady P8: B(t+2)2,A(t+2)4,B(t+3)2=8 -> VMCNT(2) leaves B(t+3).
#pragma unroll 1
  for (int j = 0; j < 8; ++j) {
    const bool st = (j < 7);
    const int u = 2 * j + 1, t2 = 2 * j + 2, t3 = 2 * j + 3;
    // P1
    ldA(0, 0); ldB(0, 0); stageA2(1, 0, u);
    BAR(); LGKM0(); mm(0, 0); BAR();
    // P2
    ldB(0, 2); stageA2(1, 1, u);
    BAR(); LGKM0(); mm(0, 2); BAR();
    // P3
    ldA(0, 4); if (st) stageB1(0, 0, t2);
    BAR(); LGKM0(); mm(4, 0); BAR();
    // P4
    if (st) stageB1(0, 1, t2);
    BAR(); LGKM0(); mm(4, 2);
    if (st) { VMCNT(2); } else { VMCNT(0); }
    BAR(); SBAR();
    // P5
    ldA(1, 0); ldB(1, 0); if (st) stageA2(0, 0, t2);
    BAR(); LGKM0(); mm(0, 0); BAR();
    // P6
    ldB(1, 2); if (st) stageA2(0, 1, t2);
    BAR(); LGKM0(); mm(0, 2); BAR();
    // P7
    ldA(1, 4); if (st) stageB1(1, 0, t3);
    BAR(); LGKM0(); mm(4, 0); BAR();
    // P8
    if (st) stageB1(1, 1, t3);
    BAR(); LGKM0(); mm(4, 2);
    if (st) { VMCNT(2); }
    BAR(); SBAR();
  }

  // ---- epilogue: per-wave [16][68] f32 strip (4352B) at smem+wid*4352
  // (all LDS dead: j=7 staged nothing new, VMCNT(0) at its P4, last ds
  // reads consumed, and every wave passed the final barrier).
  float* S = (float*)(smem + wid * 4352);
  const int crow0 = row0 + (wm << 7);
  const int ccol0 = col0 + (wn << 6);
#pragma unroll
  for (int fm = 0; fm < 8; ++fm) {
#pragma unroll
    for (int fn = 0; fn < 4; ++fn)
#pragma unroll
      for (int q = 0; q < 4; ++q)
        S[(hq * 4 + q) * 68 + fn * 16 + lr16] = acc[fm][fn][q];
#pragma unroll
    for (int r2 = 0; r2 < 4; ++r2) {
      f32x4 v = *(const f32x4*)&S[(r2 * 4 + hq) * 68 + lr16 * 4];
      __builtin_nontemporal_store(
          v, (f32x4*)&C[(size_t)(crow0 + fm * 16 + r2 * 4 + hq) * N_DIM +
                        ccol0 + lr16 * 4]);
    }
  }
}

extern "C" void kernel_launch(void* const* d_in, const int* in_sizes, int n_in,
                              void* d_out, int out_size, void* d_ws, size_t ws_size,
                              hipStream_t stream) {
  const float* x = (const float*)d_in[0];
  const float* y = (const float*)d_in[1];
  float* out = (float*)d_out;
  unsigned short* xn = (unsigned short*)d_ws;                    // 8 MB
  unsigned short* yn = xn + (size_t)M_DIM * K_DIM;               // 8 MB

  (void)hipFuncSetAttribute((const void*)cosgemm,
                            hipFuncAttributeMaxDynamicSharedMemorySize, 65536);

  normalize_rows<<<(M_DIM + N_DIM) / 4, 256, 0, stream>>>(x, y, xn);
  cosgemm<<<(M_DIM / 256) * (N_DIM / 128), 256, 49152, stream>>>(xn, yn, out);
}

// Round 14
// 107.666 us; speedup vs baseline: 1.2493x; 1.0199x over previous
//
#include <hip/hip_runtime.h>

// Pairwise cosine similarity: C[i][j] = <x_i/||x_i||, y_j/||y_j||>
// x,y: [8192][512] f32.  Out: [8192][8192] f32.
// Stage 1: row-normalize -> bf16 in d_ws (fused single launch).
// Stage 2: 256x128-tile BK=32 8-phase bf16 MFMA GEMM (R9/R13 pipeline:
//   4 waves, 48KB dbuf LDS, counted VMCNT(2), XOR swizzle, setprio,
//   serpentine XCD mapping, strip epilogue).
// R14 change (single variable vs R13): epilogue stores via inline-asm
//   global_store_dwordx4 with sc0 sc1 nt — full streaming/no-allocate
//   cache policy at ALL levels. __builtin_nontemporal_store emits only
//   `nt`; the remaining candidate for the persistent 266MB
//   write-allocate FETCH is L2/MALL allocation policy controlled by the
//   sc0/sc1 bits. Six structural levers (geometry, nt, occupancy,
//   barriers, pipeline, L2 mapping) are all proven null; this is the
//   last shader-visible knob before declaring the memory roofline.

typedef __attribute__((ext_vector_type(8))) short bf16x8;
typedef __attribute__((ext_vector_type(4))) float f32x4;
typedef __attribute__((ext_vector_type(8))) unsigned short ushort8;

#define M_DIM 8192
#define N_DIM 8192
#define K_DIM 512

static __device__ __forceinline__ unsigned short f32_to_bf16(float f) {
  unsigned int u = __float_as_uint(f);
  u = (u + 0x7FFFu + ((u >> 16) & 1u)) >> 16;  // round-to-nearest-even
  return (unsigned short)u;
}

// One wave per row; handles x rows [0,8192) and y rows [8192,16384).
__global__ __launch_bounds__(256) void normalize_rows(
    const float* __restrict__ x, const float* __restrict__ y,
    unsigned short* __restrict__ out) {
  const int wid = threadIdx.x >> 6;
  const int lane = threadIdx.x & 63;
  const int row = (blockIdx.x << 2) + wid;
  const float* src = row < M_DIM ? x + (size_t)row * K_DIM
                                 : y + (size_t)(row - M_DIM) * K_DIM;
  const float4* r = (const float4*)src;
  float4 v0 = r[lane * 2];
  float4 v1 = r[lane * 2 + 1];
  float ss = v0.x * v0.x + v0.y * v0.y + v0.z * v0.z + v0.w * v0.w +
             v1.x * v1.x + v1.y * v1.y + v1.z * v1.z + v1.w * v1.w;
#pragma unroll
  for (int off = 32; off; off >>= 1) ss += __shfl_xor(ss, off, 64);
  const float s = 1.0f / fmaxf(sqrtf(ss), 1e-8f);
  const float f[8] = {v0.x, v0.y, v0.z, v0.w, v1.x, v1.y, v1.z, v1.w};
  union { ushort8 v; unsigned short u[8]; } o;
#pragma unroll
  for (int i = 0; i < 8; ++i) o.u[i] = f32_to_bf16(f[i] * s);
  *(ushort8*)(out + (size_t)row * K_DIM + lane * 8) = o.v;
}

static __device__ __forceinline__ void gl16(const unsigned short* g, char* l) {
  __builtin_amdgcn_global_load_lds(
      (const __attribute__((address_space(1))) unsigned int*)g,
      (__attribute__((address_space(3))) unsigned int*)l, 16, 0, 0);
}

// streaming store: no-allocate at L2/MALL (sc0 sc1) + non-temporal (nt)
static __device__ __forceinline__ void store_stream(float* p, f32x4 v) {
  asm volatile("global_store_dwordx4 %0, %1, off sc0 sc1 nt"
               :: "v"(p), "v"(v) : "memory");
}

#define BAR() __builtin_amdgcn_s_barrier()
#define SBAR() __builtin_amdgcn_sched_barrier(0)
#define LGKM0() do { asm volatile("s_waitcnt lgkmcnt(0)" ::: "memory"); \
                     __builtin_amdgcn_sched_barrier(0); } while (0)
#define VMCNT(n) do { asm volatile("s_waitcnt vmcnt(" #n ")" ::: "memory"); \
                      __builtin_amdgcn_sched_barrier(0); } while (0)

// LDS per parity p: base p*24576; A [0,16K): row r (0..255) at r*64,
// slot s (16B) stored at (s ^ (r&3))*16; B [16K,24K): row (0..127) same.
__global__ __launch_bounds__(256, 2) void cosgemm(
    const unsigned short* __restrict__ A,   // xn bf16 [8192][512]
    const unsigned short* __restrict__ B,   // yn bf16 [8192][512]
    float* __restrict__ C) {                // [8192][8192]
  extern __shared__ char smem[];  // 49152 B

  const int tid = threadIdx.x;
  const int lane = tid & 63;
  const int wid = tid >> 6;       // 0..3
  const int wm = wid >> 1;        // 0..1  (M half: 128 rows)
  const int wn = wid & 1;         // 0..1  (N half: 64 cols)
  const int lr16 = lane & 15;
  const int hq = lane >> 4;       // 0..3  (k slot)
  const int sw = hq ^ (lr16 & 3); // swizzled ds_read slot (uniform/lane)

  // serpentine XCD mapping (R13): xcd owns by {4x..4x+3}; bx chunks of 8.
  const int bid = blockIdx.x;                // 0..2047
  const int xcd = bid & 7;
  const int i = bid >> 3;                    // 0..255
  const int c = i >> 5;                      // chunk 0..7
  const int r = i & 31;                      // 0..31 within chunk
  const int by = (xcd << 2) + (r & 3);       // 0..31
  const int bx = (c << 3) + (r >> 2);        // 0..63
  const int row0 = by << 8;                  // A rows (256)
  const int col0 = bx << 7;                  // B rows / C cols (128)

  // staging source: call covers row = base + c*16 + (lane>>2),
  // global 16B slot = (lane&3) ^ (row&3) = (lane&3) ^ ((lane>>2)&3).
  const int srl = lane >> 2;
  const int ssl = (lane & 3) ^ (srl & 3);
  const unsigned short* pA =
      A + (size_t)(row0 + (wid << 6) + srl) * K_DIM + ssl * 8;
  const unsigned short* pB =
      B + (size_t)(col0 + (wid << 5) + srl) * K_DIM + ssl * 8;

  // stageA2: 2 gl16 (32 rows); stageB1: 1 gl16 (16 rows). T = K-tile idx.
  auto stageA2 = [&](int par, int cpair, int T) {
    char* l = smem + par * 24576 + (wid << 12) + (cpair << 11);
    const unsigned short* g = pA + T * 32 + (size_t)(cpair << 5) * K_DIM;
    gl16(g, l);
    gl16(g + (size_t)16 * K_DIM, l + 1024);
  };
  auto stageB1 = [&](int par, int cc, int T) {
    char* l = smem + par * 24576 + 16384 + (wid << 11) + (cc << 10);
    gl16(pB + T * 32 + (size_t)(cc << 4) * K_DIM, l);
  };

  bf16x8 af[4], bf[4];
  f32x4 acc[8][4] = {};

  auto ldA = [&](int par, int fmBase) {   // 4 x ds_read_b128
#pragma unroll
    for (int j = 0; j < 4; ++j) {
      const int row = (wm << 7) + (fmBase + j) * 16 + lr16;
      af[j] = *(const bf16x8*)(smem + par * 24576 + row * 64 + (sw << 4));
    }
  };
  auto ldB = [&](int par, int fnBase) {   // 2 x ds_read_b128
#pragma unroll
    for (int j = 0; j < 2; ++j) {
      const int row = (wn << 6) + (fnBase + j) * 16 + lr16;
      bf[fnBase + j] =
          *(const bf16x8*)(smem + par * 24576 + 16384 + row * 64 + (sw << 4));
    }
  };
  auto mm = [&](int fmBase, int fnBase) {  // 8 MFMA
    __builtin_amdgcn_s_setprio(1);
#pragma unroll
    for (int m = 0; m < 4; ++m)
#pragma unroll
      for (int n = 0; n < 2; ++n)
        acc[fmBase + m][fnBase + n] = __builtin_amdgcn_mfma_f32_16x16x32_bf16(
            af[m], bf[fnBase + n], acc[fmBase + m][fnBase + n], 0, 0, 0);
    __builtin_amdgcn_s_setprio(0);
  };

  // ---- prologue: A(0), B(0), B(1); VMCNT(2) -> tile0 landed
  stageA2(0, 0, 0); stageA2(0, 1, 0);
  stageB1(0, 0, 0); stageB1(0, 1, 0);
  stageB1(1, 0, 1); stageB1(1, 1, 1);
  VMCNT(2);
  BAR(); SBAR();

  // per-wave outstanding ledger (in-order retirement):
  // steady P4: B(u)2,A(u)4,B(t+2)2=8 -> VMCNT(2) leaves B(t+2).
  // steady P8: B(t+2)2,A(t+2)4,B(t+3)2=8 -> VMCNT(2) leaves B(t+3).
#pragma unroll 1
  for (int j = 0; j < 8; ++j) {
    const bool st = (j < 7);
    const int u = 2 * j + 1, t2 = 2 * j + 2, t3 = 2 * j + 3;
    // P1
    ldA(0, 0); ldB(0, 0); stageA2(1, 0, u);
    BAR(); LGKM0(); mm(0, 0); BAR();
    // P2
    ldB(0, 2); stageA2(1, 1, u);
    BAR(); LGKM0(); mm(0, 2); BAR();
    // P3
    ldA(0, 4); if (st) stageB1(0, 0, t2);
    BAR(); LGKM0(); mm(4, 0); BAR();
    // P4
    if (st) stageB1(0, 1, t2);
    BAR(); LGKM0(); mm(4, 2);
    if (st) { VMCNT(2); } else { VMCNT(0); }
    BAR(); SBAR();
    // P5
    ldA(1, 0); ldB(1, 0); if (st) stageA2(0, 0, t2);
    BAR(); LGKM0(); mm(0, 0); BAR();
    // P6
    ldB(1, 2); if (st) stageA2(0, 1, t2);
    BAR(); LGKM0(); mm(0, 2); BAR();
    // P7
    ldA(1, 4); if (st) stageB1(1, 0, t3);
    BAR(); LGKM0(); mm(4, 0); BAR();
    // P8
    if (st) stageB1(1, 1, t3);
    BAR(); LGKM0(); mm(4, 2);
    if (st) { VMCNT(2); }
    BAR(); SBAR();
  }

  // ---- epilogue: per-wave [16][68] f32 strip (4352B) at smem+wid*4352;
  // all LDS dead. Stores: streaming sc0 sc1 nt dwordx4.
  float* S = (float*)(smem + wid * 4352);
  const int crow0 = row0 + (wm << 7);
  const int ccol0 = col0 + (wn << 6);
#pragma unroll
  for (int fm = 0; fm < 8; ++fm) {
#pragma unroll
    for (int fn = 0; fn < 4; ++fn)
#pragma unroll
      for (int q = 0; q < 4; ++q)
        S[(hq * 4 + q) * 68 + fn * 16 + lr16] = acc[fm][fn][q];
#pragma unroll
    for (int r2 = 0; r2 < 4; ++r2) {
      f32x4 v = *(const f32x4*)&S[(r2 * 4 + hq) * 68 + lr16 * 4];
      store_stream(&C[(size_t)(crow0 + fm * 16 + r2 * 4 + hq) * N_DIM +
                      ccol0 + lr16 * 4], v);
    }
  }
}

extern "C" void kernel_launch(void* const* d_in, const int* in_sizes, int n_in,
                              void* d_out, int out_size, void* d_ws, size_t ws_size,
                              hipStream_t stream) {
  const float* x = (const float*)d_in[0];
  const float* y = (const float*)d_in[1];
  float* out = (float*)d_out;
  unsigned short* xn = (unsigned short*)d_ws;                    // 8 MB
  unsigned short* yn = xn + (size_t)M_DIM * K_DIM;               // 8 MB

  (void)hipFuncSetAttribute((const void*)cosgemm,
                            hipFuncAttributeMaxDynamicSharedMemorySize, 65536);

  normalize_rows<<<(M_DIM + N_DIM) / 4, 256, 0, stream>>>(x, y, xn);
  cosgemm<<<(M_DIM / 256) * (N_DIM / 128), 256, 49152, stream>>>(xn, yn, out);
}